// Round 1
// baseline (273.248 us; speedup 1.0000x reference)
//
#include <hip/hip_runtime.h>

#define BATCH  8
#define SEQ    2048
#define DIMSZ  1024
#define NST    16
#define LCH    32               // chunk length
#define CPB    (SEQ / LCH)      // 64 chunks per batch
#define NCHUNK (BATCH * CPB)    // 512
#define NCHEB  32               // Chebyshev terms (degree 31)

typedef __attribute__((ext_vector_type(8))) short bf16x8;
typedef __attribute__((ext_vector_type(4))) float f32x4;

static __device__ __forceinline__ unsigned short f2bf(float f) {
    unsigned u = __builtin_bit_cast(unsigned, f);
    unsigned r = (u + 0x7FFFu + ((u >> 16) & 1u)) >> 16;
    return (unsigned short)r;
}
static __device__ __forceinline__ float bf2f(unsigned short h) {
    unsigned u = ((unsigned)h) << 16;
    return __builtin_bit_cast(float, u);
}

// ---------------------------------------------------------------------------
// sA: F_k = expm(delta_k * A) at the 32 Chebyshev nodes delta_k in (0,1).
// Taylor-8 + 6 squarings (verified). 32 blocks.
// ---------------------------------------------------------------------------
__global__ __launch_bounds__(256) void sA_nodes(
    const float* __restrict__ A_log, float* __restrict__ Fn)
{
    __shared__ float Xs[16 * 17];
    __shared__ float Ts[16 * 17];
    const int tid = threadIdx.x;
    const int i = tid >> 4, j = tid & 15;
    const float th = (2.f * blockIdx.x + 1.f) * (3.14159265358979f / 64.f);
    const float dl = 0.5f * (1.f + cosf(th));
    const float a  = -expf(A_log[tid]);
    const float x  = dl * a * (1.0f / 64.0f);     // s = 6
    Xs[i*17 + j] = x;
    Ts[i*17 + j] = x;
    float S = x + (i == j ? 1.0f : 0.0f);
    __syncthreads();
#pragma unroll
    for (int k = 2; k <= 8; ++k) {
        float nt = 0.f;
#pragma unroll
        for (int kk = 0; kk < 16; ++kk)
            nt = fmaf(Ts[i*17 + kk], Xs[kk*17 + j], nt);
        nt *= (1.0f / (float)k);
        S += nt;
        __syncthreads();
        Ts[i*17 + j] = nt;
        __syncthreads();
    }
#pragma unroll
    for (int r = 0; r < 6; ++r) {
        __syncthreads();
        Ts[i*17 + j] = S;
        __syncthreads();
        float nt = 0.f;
#pragma unroll
        for (int kk = 0; kk < 16; ++kk)
            nt = fmaf(Ts[i*17 + kk], Ts[kk*17 + j], nt);
        S = nt;
    }
    Fn[(size_t)blockIdx.x * 256 + tid] = S;
}

// ---------------------------------------------------------------------------
// sB: blocks 0..31  -> Chebyshev coefficient m = blockIdx.x (thread = element)
//     blocks 32..39 -> bf16 hi/lo MFMA B-operand fragments for B_mat / dt_w
// ---------------------------------------------------------------------------
__global__ __launch_bounds__(256) void sB_setup(
    const float* __restrict__ Fn, const float* __restrict__ B_mat,
    const float* __restrict__ dt_w,
    float* __restrict__ Gt,
    unsigned short* __restrict__ Bfh, unsigned short* __restrict__ Bfl,
    unsigned short* __restrict__ Wfh, unsigned short* __restrict__ Wfl)
{
    const int tid = threadIdx.x;
    const int blk = blockIdx.x;
    if (blk < NCHEB) {
        const int m = blk;
        float acc = 0.f;
        for (int k = 0; k < NCHEB; ++k) {
            const float th = (2.f * k + 1.f) * (3.14159265358979f / 64.f);
            acc = fmaf(Fn[(size_t)k * 256 + tid], cosf(m * th), acc);
        }
        const float sc = (m == 0) ? (1.f / 32.f) : (2.f / 32.f);
        Gt[(size_t)tid * NCHEB + m] = acc * sc;
    } else {
        const int idx0 = (blk - NCHEB) * 2048;
        for (int t = 0; t < 8; ++t) {
            const int idx = idx0 + t * 256 + tid;
            const int j  = idx & 7;
            const int l  = (idx >> 3) & 63;
            const int ks = idx >> 9;
            const int k  = ks * 32 + ((l >> 4) << 3) + j;
            const int n  = l & 15;
            float bv = B_mat[(size_t)k * 16 + n];
            unsigned short h = f2bf(bv);
            Bfh[idx] = h;
            Bfl[idx] = f2bf(bv - bf2f(h));
            float wv = (n == 0) ? dt_w[k] : 0.f;
            h = f2bf(wv);
            Wfh[idx] = h;
            Wfl[idx] = f2bf(wv - bf2f(h));
        }
    }
}

// ---------------------------------------------------------------------------
// k1: Bu = u @ B and delta-dot via bf16-split MFMA. Block = 16 tokens;
// 4 waves K-split (each wave K=256), LDS reduce of partial accumulators.
// v2: explicit register software pipeline — u/gate prefetched 4 iterations
// ahead, MFMA B-fragments prefetched 2 ahead. Previous version had fragment
// loads consumed in-iteration (raw L2 round-trip every iter) and depth-1
// u/gate prefetch: latency-bound at 56 us (MfmaUtil 2%, VALUBusy 10%,
// VGPR=36 => compiler hoisted nothing). launch_bounds(256,2) gives the
// allocator room (~140 VGPR) for the pipeline.
// ---------------------------------------------------------------------------
__global__ __launch_bounds__(256, 2) void k1_mfma(
    const float* __restrict__ u, const float* __restrict__ gate,
    const unsigned short* __restrict__ Bfh, const unsigned short* __restrict__ Bfl,
    const unsigned short* __restrict__ Wfh, const unsigned short* __restrict__ Wfl,
    const float* __restrict__ dt_b,
    float* __restrict__ delta, float* __restrict__ Bu)
{
    __shared__ float r0[4 * 256];
    __shared__ float r1[4 * 256];
    const int tid  = threadIdx.x;
    const int lane = tid & 63;
    const int wv   = tid >> 6;
    const size_t m0 = (size_t)blockIdx.x * 16;
    const int mrow = lane & 15;
    const int q    = lane >> 4;
    const float* up = u    + (m0 + mrow) * DIMSZ + q * 8;
    const float* gp = gate + (m0 + mrow) * DIMSZ + q * 8;
    const uint4* bh = (const uint4*)Bfh;
    const uint4* bl = (const uint4*)Bfl;
    const uint4* wh = (const uint4*)Wfh;
    const uint4* wl = (const uint4*)Wfl;
    const int ksBase = wv * 8;

    f32x4 acc0 = {0.f, 0.f, 0.f, 0.f};
    f32x4 acc1 = {0.f, 0.f, 0.f, 0.f};

    // Software-pipeline register buffers (static indices after full unroll;
    // live ranges: u/gate 4 iters, fragments 2 iters).
    float4 ua[8], ub[8], ga[8], gb[8];
    uint4  fbh[8], fbl[8], fwh[8], fwl[8];

#pragma unroll
    for (int p = 0; p < 4; ++p) {
        ua[p] = *(const float4*)(up + (ksBase + p) * 32);
        ub[p] = *(const float4*)(up + (ksBase + p) * 32 + 4);
        ga[p] = *(const float4*)(gp + (ksBase + p) * 32);
        gb[p] = *(const float4*)(gp + (ksBase + p) * 32 + 4);
    }
#pragma unroll
    for (int p = 0; p < 2; ++p) {
        fbh[p] = bh[(ksBase + p) * 64 + lane];
        fbl[p] = bl[(ksBase + p) * 64 + lane];
        fwh[p] = wh[(ksBase + p) * 64 + lane];
        fwl[p] = wl[(ksBase + p) * 64 + lane];
    }

#pragma unroll
    for (int t = 0; t < 8; ++t) {
        if (t + 4 < 8) {
            ua[t + 4] = *(const float4*)(up + (ksBase + t + 4) * 32);
            ub[t + 4] = *(const float4*)(up + (ksBase + t + 4) * 32 + 4);
            ga[t + 4] = *(const float4*)(gp + (ksBase + t + 4) * 32);
            gb[t + 4] = *(const float4*)(gp + (ksBase + t + 4) * 32 + 4);
        }
        if (t + 2 < 8) {
            fbh[t + 2] = bh[(ksBase + t + 2) * 64 + lane];
            fbl[t + 2] = bl[(ksBase + t + 2) * 64 + lane];
            fwh[t + 2] = wh[(ksBase + t + 2) * 64 + lane];
            fwl[t + 2] = wl[(ksBase + t + 2) * 64 + lane];
        }
        const float fu[8] = {ua[t].x, ua[t].y, ua[t].z, ua[t].w,
                             ub[t].x, ub[t].y, ub[t].z, ub[t].w};
        const float fg[8] = {ga[t].x, ga[t].y, ga[t].z, ga[t].w,
                             gb[t].x, gb[t].y, gb[t].z, gb[t].w};
        bf16x8 uh, ul, gh, gl;
#pragma unroll
        for (int i = 0; i < 8; ++i) {
            unsigned short h = f2bf(fu[i]);
            uh[i] = (short)h; ul[i] = (short)f2bf(fu[i] - bf2f(h));
            h = f2bf(fg[i]);
            gh[i] = (short)h; gl[i] = (short)f2bf(fg[i] - bf2f(h));
        }
        const bf16x8 Bh = __builtin_bit_cast(bf16x8, fbh[t]);
        const bf16x8 Bl = __builtin_bit_cast(bf16x8, fbl[t]);
        const bf16x8 Wh = __builtin_bit_cast(bf16x8, fwh[t]);
        const bf16x8 Wl = __builtin_bit_cast(bf16x8, fwl[t]);
        acc0 = __builtin_amdgcn_mfma_f32_16x16x32_bf16(uh, Bh, acc0, 0, 0, 0);
        acc0 = __builtin_amdgcn_mfma_f32_16x16x32_bf16(uh, Bl, acc0, 0, 0, 0);
        acc0 = __builtin_amdgcn_mfma_f32_16x16x32_bf16(ul, Bh, acc0, 0, 0, 0);
        acc1 = __builtin_amdgcn_mfma_f32_16x16x32_bf16(gh, Wh, acc1, 0, 0, 0);
        acc1 = __builtin_amdgcn_mfma_f32_16x16x32_bf16(gh, Wl, acc1, 0, 0, 0);
        acc1 = __builtin_amdgcn_mfma_f32_16x16x32_bf16(gl, Wh, acc1, 0, 0, 0);
    }
    // C layout: col(n) = lane&15, row(token) = q*4 + r
    const int n = lane & 15;
#pragma unroll
    for (int r = 0; r < 4; ++r) {
        r0[wv * 256 + (q * 4 + r) * 16 + n] = acc0[r];
        r1[wv * 256 + (q * 4 + r) * 16 + n] = acc1[r];
    }
    __syncthreads();
    const float b = r0[tid] + r0[256 + tid] + r0[512 + tid] + r0[768 + tid];
    Bu[m0 * NST + tid] = b;          // (m0 + tid/16)*16 + tid%16 == m0*16 + tid
    if (tid < 16) {
        const float dacc = r1[tid * 16] + r1[256 + tid * 16] +
                           r1[512 + tid * 16] + r1[768 + tid * 16];
        delta[m0 + tid] = 1.0f / (1.0f + expf(-(dacc + dt_b[0])));
    }
}

// ---------------------------------------------------------------------------
// kA: per chunk — M_t via register Chebyshev eval, e_c via wave-0 replay,
// P_c = F(sum/32)^32 (5 LDS squarings).
// ---------------------------------------------------------------------------
__global__ __launch_bounds__(256) void kA_chunk(
    const float* __restrict__ Gt, const float* __restrict__ delta,
    const float* __restrict__ Bu,
    float* __restrict__ P, float* __restrict__ e)
{
    __shared__ float dl[LCH];
    __shared__ float sd[1];
    __shared__ float Bus[LCH * NST];
    __shared__ float Mlds[LCH * 256];
    __shared__ float Ps[16 * 17];
    const int tid = threadIdx.x;
    const size_t g = blockIdx.x;
    if (tid < LCH) dl[tid] = delta[g * LCH + tid];
    for (int idx = tid; idx < LCH * NST; idx += 256)
        Bus[idx] = Bu[g * (size_t)(LCH * NST) + idx];
    float gr[NCHEB];
    {
        const float4* gp = (const float4*)(Gt + (size_t)tid * NCHEB);
#pragma unroll
        for (int qq = 0; qq < NCHEB / 4; ++qq) {
            float4 v = gp[qq];
            gr[qq*4+0] = v.x; gr[qq*4+1] = v.y; gr[qq*4+2] = v.z; gr[qq*4+3] = v.w;
        }
    }
    __syncthreads();
    if (tid == 0) {
        float s = 0.f;
        for (int t = 0; t < LCH; ++t) s += dl[t];
        sd[0] = s;
    }
    for (int t = 0; t < LCH; ++t) {
        const float x = 2.f * dl[t] - 1.f;
        float acc = fmaf(gr[1], x, gr[0]);
        float tm2 = 1.f, tm1 = x;
#pragma unroll
        for (int m = 2; m < NCHEB; ++m) {
            const float tm = fmaf(2.f * x, tm1, -tm2);
            acc = fmaf(gr[m], tm, acc);
            tm2 = tm1; tm1 = tm;
        }
        Mlds[t * 256 + tid] = acc;
    }
    __syncthreads();
    float S;
    {
        const float xp = 2.f * (sd[0] * (1.f / LCH)) - 1.f;
        float acc = fmaf(gr[1], xp, gr[0]);
        float tm2 = 1.f, tm1 = xp;
#pragma unroll
        for (int m = 2; m < NCHEB; ++m) {
            const float tm = fmaf(2.f * xp, tm1, -tm2);
            acc = fmaf(gr[m], tm, acc);
            tm2 = tm1; tm1 = tm;
        }
        S = acc;
    }
    const int i = tid >> 4, j = tid & 15;
#pragma unroll
    for (int r = 0; r < 5; ++r) {
        Ps[i*17 + j] = S;
        __syncthreads();
        float ns = 0.f;
#pragma unroll
        for (int k = 0; k < 16; ++k)
            ns = fmaf(Ps[i*17 + k], Ps[k*17 + j], ns);
        __syncthreads();
        S = ns;
    }
    P[g * 256 + tid] = S;
    if (tid < 16) {
        float h = 0.f;
        for (int t = 0; t < LCH; ++t) {
            float hn = Bus[t * 16 + tid];
#pragma unroll
            for (int i2 = 0; i2 < 16; ++i2)
                hn = fmaf(__shfl(h, i2, 64), Mlds[t * 256 + i2 * 16 + tid], hn);
            h = hn;
        }
        e[g * NST + tid] = h;
    }
}

// ---------------------------------------------------------------------------
// k4: serial scan over the 64 chunk summaries of each batch.
// ---------------------------------------------------------------------------
__global__ __launch_bounds__(256) void k4_scan(
    const float* __restrict__ P, const float* __restrict__ e,
    float* __restrict__ hin)
{
    __shared__ float Pl[32 * 272];
    __shared__ float el[32 * NST];
    const int tid = threadIdx.x;
    const int b = blockIdx.x;
    float h = 0.f;
    for (int half = 0; half < 2; ++half) {
        const int c0 = half * 32;
        for (int idx = tid; idx < 32*256; idx += 256) {
            const int c = idx >> 8, ij = idx & 255, i = ij >> 4, jj = ij & 15;
            Pl[c*272 + i*17 + jj] = P[((size_t)(b*CPB + c0 + c)) * 256 + ij];
        }
        for (int idx = tid; idx < 32*NST; idx += 256)
            el[idx] = e[((size_t)(b*CPB + c0)) * NST + idx];
        __syncthreads();
        if (tid < 64) {
            const int j = tid & 15;
            for (int c = 0; c < 32; ++c) {
                if (tid < 16) hin[((size_t)(b*CPB + c0 + c)) * NST + j] = h;
                float hn = el[c*16 + j];
#pragma unroll
                for (int i2 = 0; i2 < 16; ++i2)
                    hn = fmaf(__shfl(h, i2, 64), Pl[c*272 + i2*17 + j], hn);
                h = hn;
            }
        }
        __syncthreads();
    }
}

// ---------------------------------------------------------------------------
// k5: recompute M from delta (register Chebyshev), replay from hin, fused
// projection y = h C^T + D*u.
// ---------------------------------------------------------------------------
__global__ __launch_bounds__(256) void k5_out(
    const float* __restrict__ Gt, const float* __restrict__ delta,
    const float* __restrict__ Bu, const float* __restrict__ hin,
    const float* __restrict__ u, const float* __restrict__ C_mat,
    const float* __restrict__ D, float* __restrict__ y)
{
    __shared__ float dl[LCH];
    __shared__ float Bus[LCH * NST];
    __shared__ float Mlds[LCH * 256];
    __shared__ __align__(16) float Hs[LCH * NST];
    const int tid = threadIdx.x;
    const size_t g = blockIdx.x;
    if (tid < LCH) dl[tid] = delta[g * LCH + tid];
    for (int idx = tid; idx < LCH * NST; idx += 256)
        Bus[idx] = Bu[g * (size_t)(LCH * NST) + idx];
    float gr[NCHEB];
    {
        const float4* gp = (const float4*)(Gt + (size_t)tid * NCHEB);
#pragma unroll
        for (int qq = 0; qq < NCHEB / 4; ++qq) {
            float4 v = gp[qq];
            gr[qq*4+0] = v.x; gr[qq*4+1] = v.y; gr[qq*4+2] = v.z; gr[qq*4+3] = v.w;
        }
    }
    __syncthreads();
    for (int t = 0; t < LCH; ++t) {
        const float x = 2.f * dl[t] - 1.f;
        float acc = fmaf(gr[1], x, gr[0]);
        float tm2 = 1.f, tm1 = x;
#pragma unroll
        for (int m = 2; m < NCHEB; ++m) {
            const float tm = fmaf(2.f * x, tm1, -tm2);
            acc = fmaf(gr[m], tm, acc);
            tm2 = tm1; tm1 = tm;
        }
        Mlds[t * 256 + tid] = acc;
    }
    __syncthreads();
    if (tid < 16) {
        float h = hin[g * NST + tid];
        for (int t = 0; t < LCH; ++t) {
            float hn = Bus[t * 16 + tid];
#pragma unroll
            for (int i2 = 0; i2 < 16; ++i2)
                hn = fmaf(__shfl(h, i2, 64), Mlds[t * 256 + i2 * 16 + tid], hn);
            h = hn;
            Hs[t * 16 + tid] = h;
        }
    }
    __syncthreads();
    const int d0 = tid * 4;
    float4 cr[4][4];
#pragma unroll
    for (int r = 0; r < 4; ++r)
#pragma unroll
        for (int qq = 0; qq < 4; ++qq)
            cr[r][qq] = ((const float4*)C_mat)[(d0 + r) * 4 + qq];
    const float4 dv = ((const float4*)D)[tid];
    for (int t = 0; t < LCH; ++t) {
        const size_t row = (g * LCH + t) * DIMSZ;
        const float4 uv = ((const float4*)(u + row))[tid];
        float y0 = dv.x * uv.x, y1 = dv.y * uv.y, y2 = dv.z * uv.z, y3 = dv.w * uv.w;
#pragma unroll
        for (int qq = 0; qq < 4; ++qq) {
            const float4 hq = *((const float4*)&Hs[t*16 + qq*4]);
            y0 = fmaf(hq.x, cr[0][qq].x, y0); y0 = fmaf(hq.y, cr[0][qq].y, y0);
            y0 = fmaf(hq.z, cr[0][qq].z, y0); y0 = fmaf(hq.w, cr[0][qq].w, y0);
            y1 = fmaf(hq.x, cr[1][qq].x, y1); y1 = fmaf(hq.y, cr[1][qq].y, y1);
            y1 = fmaf(hq.z, cr[1][qq].z, y1); y1 = fmaf(hq.w, cr[1][qq].w, y1);
            y2 = fmaf(hq.x, cr[2][qq].x, y2); y2 = fmaf(hq.y, cr[2][qq].y, y2);
            y2 = fmaf(hq.z, cr[2][qq].z, y2); y2 = fmaf(hq.w, cr[2][qq].w, y2);
            y3 = fmaf(hq.x, cr[3][qq].x, y3); y3 = fmaf(hq.y, cr[3][qq].y, y3);
            y3 = fmaf(hq.z, cr[3][qq].z, y3); y3 = fmaf(hq.w, cr[3][qq].w, y3);
        }
        float4 ov; ov.x = y0; ov.y = y1; ov.z = y2; ov.w = y3;
        ((float4*)(y + row))[tid] = ov;
    }
}

// ---------------------------------------------------------------------------
extern "C" void kernel_launch(void* const* d_in, const int* in_sizes, int n_in,
                              void* d_out, int out_size, void* d_ws, size_t ws_size,
                              hipStream_t stream)
{
    const float* u     = (const float*)d_in[0];
    const float* gate  = (const float*)d_in[1];
    const float* A_log = (const float*)d_in[2];
    const float* B_mat = (const float*)d_in[3];
    const float* C_mat = (const float*)d_in[4];
    const float* D     = (const float*)d_in[5];
    const float* dt_w  = (const float*)d_in[6];
    const float* dt_b  = (const float*)d_in[7];
    float* y = (float*)d_out;

    float* ws = (float*)d_ws;
    size_t o = 0;
    float* Fn    = ws + o; o += 32 * 256;
    float* Gt    = ws + o; o += 256 * NCHEB;
    float* delta = ws + o; o += (size_t)BATCH * SEQ;
    float* Bu    = ws + o; o += (size_t)BATCH * SEQ * NST;
    float* P     = ws + o; o += (size_t)NCHUNK * 256;
    float* e     = ws + o; o += (size_t)NCHUNK * NST;
    float* hin   = ws + o; o += (size_t)NCHUNK * NST;
    unsigned short* Bfh = (unsigned short*)(ws + o); o += 8192;
    unsigned short* Bfl = (unsigned short*)(ws + o); o += 8192;
    unsigned short* Wfh = (unsigned short*)(ws + o); o += 8192;
    unsigned short* Wfl = (unsigned short*)(ws + o); o += 8192;

    sA_nodes<<<NCHEB, 256, 0, stream>>>(A_log, Fn);
    sB_setup<<<NCHEB + 8, 256, 0, stream>>>(Fn, B_mat, dt_w, Gt, Bfh, Bfl, Wfh, Wfl);
    k1_mfma <<<BATCH * SEQ / 16, 256, 0, stream>>>(u, gate, Bfh, Bfl, Wfh, Wfl,
                                                   dt_b, delta, Bu);
    kA_chunk<<<NCHUNK, 256, 0, stream>>>(Gt, delta, Bu, P, e);
    k4_scan <<<BATCH,  256, 0, stream>>>(P, e, hin);
    k5_out  <<<NCHUNK, 256, 0, stream>>>(Gt, delta, Bu, hin, u, C_mat, D, y);
}

// Round 2
// 267.192 us; speedup vs baseline: 1.0227x; 1.0227x over previous
//
#include <hip/hip_runtime.h>

#define BATCH  8
#define SEQ    2048
#define DIMSZ  1024
#define NST    16
#define LCH    32               // chunk length
#define CPB    (SEQ / LCH)      // 64 chunks per batch
#define NCHUNK (BATCH * CPB)    // 512
#define NCHEB  32               // Chebyshev terms (degree 31)

typedef __attribute__((ext_vector_type(8))) short bf16x8;
typedef __attribute__((ext_vector_type(4))) float f32x4;

static __device__ __forceinline__ unsigned short f2bf(float f) {
    unsigned u = __builtin_bit_cast(unsigned, f);
    unsigned r = (u + 0x7FFFu + ((u >> 16) & 1u)) >> 16;
    return (unsigned short)r;
}
static __device__ __forceinline__ float bf2f(unsigned short h) {
    unsigned u = ((unsigned)h) << 16;
    return __builtin_bit_cast(float, u);
}

// ---------------------------------------------------------------------------
// sA: F_k = expm(delta_k * A) at the 32 Chebyshev nodes delta_k in (0,1).
// Taylor-8 + 6 squarings (verified). 32 blocks.
// ---------------------------------------------------------------------------
__global__ __launch_bounds__(256) void sA_nodes(
    const float* __restrict__ A_log, float* __restrict__ Fn)
{
    __shared__ float Xs[16 * 17];
    __shared__ float Ts[16 * 17];
    const int tid = threadIdx.x;
    const int i = tid >> 4, j = tid & 15;
    const float th = (2.f * blockIdx.x + 1.f) * (3.14159265358979f / 64.f);
    const float dl = 0.5f * (1.f + cosf(th));
    const float a  = -expf(A_log[tid]);
    const float x  = dl * a * (1.0f / 64.0f);     // s = 6
    Xs[i*17 + j] = x;
    Ts[i*17 + j] = x;
    float S = x + (i == j ? 1.0f : 0.0f);
    __syncthreads();
#pragma unroll
    for (int k = 2; k <= 8; ++k) {
        float nt = 0.f;
#pragma unroll
        for (int kk = 0; kk < 16; ++kk)
            nt = fmaf(Ts[i*17 + kk], Xs[kk*17 + j], nt);
        nt *= (1.0f / (float)k);
        S += nt;
        __syncthreads();
        Ts[i*17 + j] = nt;
        __syncthreads();
    }
#pragma unroll
    for (int r = 0; r < 6; ++r) {
        __syncthreads();
        Ts[i*17 + j] = S;
        __syncthreads();
        float nt = 0.f;
#pragma unroll
        for (int kk = 0; kk < 16; ++kk)
            nt = fmaf(Ts[i*17 + kk], Ts[kk*17 + j], nt);
        S = nt;
    }
    Fn[(size_t)blockIdx.x * 256 + tid] = S;
}

// ---------------------------------------------------------------------------
// sB: blocks 0..31  -> Chebyshev coefficient m = blockIdx.x (thread = element)
//     blocks 32..39 -> bf16 hi/lo MFMA B-operand fragments for B_mat / dt_w
// ---------------------------------------------------------------------------
__global__ __launch_bounds__(256) void sB_setup(
    const float* __restrict__ Fn, const float* __restrict__ B_mat,
    const float* __restrict__ dt_w,
    float* __restrict__ Gt,
    unsigned short* __restrict__ Bfh, unsigned short* __restrict__ Bfl,
    unsigned short* __restrict__ Wfh, unsigned short* __restrict__ Wfl)
{
    const int tid = threadIdx.x;
    const int blk = blockIdx.x;
    if (blk < NCHEB) {
        const int m = blk;
        float acc = 0.f;
        for (int k = 0; k < NCHEB; ++k) {
            const float th = (2.f * k + 1.f) * (3.14159265358979f / 64.f);
            acc = fmaf(Fn[(size_t)k * 256 + tid], cosf(m * th), acc);
        }
        const float sc = (m == 0) ? (1.f / 32.f) : (2.f / 32.f);
        Gt[(size_t)tid * NCHEB + m] = acc * sc;
    } else {
        const int idx0 = (blk - NCHEB) * 2048;
        for (int t = 0; t < 8; ++t) {
            const int idx = idx0 + t * 256 + tid;
            const int j  = idx & 7;
            const int l  = (idx >> 3) & 63;
            const int ks = idx >> 9;
            const int k  = ks * 32 + ((l >> 4) << 3) + j;
            const int n  = l & 15;
            float bv = B_mat[(size_t)k * 16 + n];
            unsigned short h = f2bf(bv);
            Bfh[idx] = h;
            Bfl[idx] = f2bf(bv - bf2f(h));
            float wv = (n == 0) ? dt_w[k] : 0.f;
            h = f2bf(wv);
            Wfh[idx] = h;
            Wfl[idx] = f2bf(wv - bf2f(h));
        }
    }
}

// ---------------------------------------------------------------------------
// k1a: delta = sigmoid(gate . dt_w + b). Pure streaming reduction, one wave
// per token, fully coalesced float4 loads, 64-lane shuffle reduce. f32 exact
// (more accurate than the old bf16-split MFMA path).
// ---------------------------------------------------------------------------
__global__ __launch_bounds__(256) void k1a_delta(
    const float* __restrict__ gate, const float* __restrict__ dt_w,
    const float* __restrict__ dt_b, float* __restrict__ delta)
{
    const int tid  = threadIdx.x;
    const int lane = tid & 63;
    const int w    = tid >> 6;
    const int tok  = blockIdx.x * 4 + w;
    const float* gp = gate + (size_t)tok * DIMSZ;
    float s = 0.f;
#pragma unroll
    for (int i = 0; i < 4; ++i) {
        const float4 g  = *(const float4*)(gp   + i * 256 + lane * 4);
        const float4 wv = *(const float4*)(dt_w + i * 256 + lane * 4);
        s = fmaf(g.x, wv.x, s); s = fmaf(g.y, wv.y, s);
        s = fmaf(g.z, wv.z, s); s = fmaf(g.w, wv.w, s);
    }
#pragma unroll
    for (int off = 32; off >= 1; off >>= 1)
        s += __shfl_xor(s, off, 64);
    if (lane == 0)
        delta[tok] = 1.0f / (1.0f + expf(-(s + dt_b[0])));
}

// ---------------------------------------------------------------------------
// k1b: Bu = u @ B via bf16 hi/lo split MFMA, u staged through LDS with
// global_load_lds (width 16, fire-and-forget), double-buffered, depth-2
// prefetch, counted vmcnt (never 0 mid-loop), raw s_barrier + sched_barrier.
// Tile: 32 tokens x 128 k-floats per chunk (two 64-float K-half regions);
// 4 waves = 2 token-tiles x 2 K-halves; 8 chunks cover K=1024.
// LDS layout is XOR-swizzled (16B chunk index ^ (row&15)) applied to the
// GLOBAL source address (dest stays linear as global_load_lds requires) and
// to the ds_read address -> A-fragment reads are bank-conflict-free.
// ---------------------------------------------------------------------------
__global__ __launch_bounds__(256, 2) void k1b_bu(
    const float* __restrict__ u,
    const unsigned short* __restrict__ Bfh, const unsigned short* __restrict__ Bfl,
    float* __restrict__ Bu)
{
    __shared__ float lds[2][32 * 128];      // 2 x 16 KB
    const int tid  = threadIdx.x;
    const int lane = tid & 63;
    const int w    = tid >> 6;
    const int tok0 = blockIdx.x * 32;
    const int half = w & 1;                 // K-half (0: k<512, 1: k>=512)
    const int wrow = (w >> 1) * 16;         // token-tile base row
    const int q    = lane >> 4;
    const int r    = lane & 15;

    const uint4* bh = (const uint4*)Bfh;
    const uint4* bl = (const uint4*)Bfl;

    // staging geometry: inst i covers rows 8w+2i .. +1 (lane>>5), 16B chunk
    // p = lane&31 (physical). logical chunk lc = (p&16) | ((p&15) ^ (row&15)).
    const int srow = 8 * w + (lane >> 5);
    const int p    = lane & 31;
    int colb[4];
#pragma unroll
    for (int i = 0; i < 4; ++i) {
        const int row = srow + 2 * i;
        const int lc  = (p & 16) | ((p & 15) ^ (row & 15));
        colb[i] = ((lc & 16) ? 512 : 0) + (lc & 15) * 4;   // float offset in row
    }

    auto stage = [&](int c, int b) {
#pragma unroll
        for (int i = 0; i < 4; ++i) {
            const float* g = u + (size_t)(tok0 + srow + 2 * i) * DIMSZ
                               + (colb[i] + c * 64);
            __builtin_amdgcn_global_load_lds(
                (const __attribute__((address_space(1))) void*)g,
                (__attribute__((address_space(3))) void*)&lds[b][(8 * w + 2 * i) * 128],
                16, 0, 0);
        }
    };

    f32x4 acc = {0.f, 0.f, 0.f, 0.f};
    uint4 fh[2][2], fl[2][2];

    // prologue: stage chunks 0,1; load frags(0); wait chunk 0 landed.
    stage(0, 0);
    stage(1, 1);
    {
        const int ks0 = half * 16;
        fh[0][0] = bh[(ks0 + 0) * 64 + lane]; fl[0][0] = bl[(ks0 + 0) * 64 + lane];
        fh[0][1] = bh[(ks0 + 1) * 64 + lane]; fl[0][1] = bl[(ks0 + 1) * 64 + lane];
    }
    asm volatile("s_waitcnt vmcnt(8)" ::: "memory");   // keep stage(1)+frags(0)
    __builtin_amdgcn_sched_barrier(0);
    __builtin_amdgcn_s_barrier();

#pragma unroll
    for (int c = 0; c < 8; ++c) {
        const int b = c & 1;
        // A-fragment ds_reads (swizzled) -> f32 regs
        float fu[2][8];
#pragma unroll
        for (int s = 0; s < 2; ++s) {
            const int c16a = (s * 8 + 2 * q + 0) ^ r;
            const int c16b = (s * 8 + 2 * q + 1) ^ r;
            const float4 v0 = *(const float4*)&lds[b][(wrow + r) * 128 + (half * 16 + c16a) * 4];
            const float4 v1 = *(const float4*)&lds[b][(wrow + r) * 128 + (half * 16 + c16b) * 4];
            fu[s][0] = v0.x; fu[s][1] = v0.y; fu[s][2] = v0.z; fu[s][3] = v0.w;
            fu[s][4] = v1.x; fu[s][5] = v1.y; fu[s][6] = v1.z; fu[s][7] = v1.w;
        }
        asm volatile("s_waitcnt lgkmcnt(0)" ::: "memory");
        __builtin_amdgcn_sched_barrier(0);
        __builtin_amdgcn_s_barrier();          // all waves done reading buf b
        // issue next-next stage into the buffer we just finished reading
        if (c + 2 < 8) stage(c + 2, b);
        // prefetch next chunk's B-fragments (L2-hot)
        if (c + 1 < 8) {
            const int ks0 = half * 16 + 2 * (c + 1);
            fh[(c + 1) & 1][0] = bh[(ks0 + 0) * 64 + lane];
            fl[(c + 1) & 1][0] = bl[(ks0 + 0) * 64 + lane];
            fh[(c + 1) & 1][1] = bh[(ks0 + 1) * 64 + lane];
            fl[(c + 1) & 1][1] = bl[(ks0 + 1) * 64 + lane];
        }
        __builtin_amdgcn_sched_barrier(0);     // pin all VMEM issues above
        // convert + MFMA (register-only)
#pragma unroll
        for (int s = 0; s < 2; ++s) {
            bf16x8 uh, ul;
#pragma unroll
            for (int i = 0; i < 8; ++i) {
                unsigned short h = f2bf(fu[s][i]);
                uh[i] = (short)h;
                ul[i] = (short)f2bf(fu[s][i] - bf2f(h));
            }
            const bf16x8 Bh = __builtin_bit_cast(bf16x8, fh[b][s]);
            const bf16x8 Bl = __builtin_bit_cast(bf16x8, fl[b][s]);
            acc = __builtin_amdgcn_mfma_f32_16x16x32_bf16(uh, Bh, acc, 0, 0, 0);
            acc = __builtin_amdgcn_mfma_f32_16x16x32_bf16(uh, Bl, acc, 0, 0, 0);
            acc = __builtin_amdgcn_mfma_f32_16x16x32_bf16(ul, Bh, acc, 0, 0, 0);
        }
        if (c < 7) {
            // wait for stage(c+1); keep {stage(c+2), frags(c+2..)} in flight
            if (c < 6) asm volatile("s_waitcnt vmcnt(8)" ::: "memory");
            else       asm volatile("s_waitcnt vmcnt(4)" ::: "memory");
            __builtin_amdgcn_sched_barrier(0);
            __builtin_amdgcn_s_barrier();
        }
    }

    // cross-wave K-half reduce via LDS (reuse buffer 0 region; all reads of
    // buf0 finished before the c=6 barrier).
    float* red = &lds[0][0];
#pragma unroll
    for (int rr = 0; rr < 4; ++rr)
        red[w * 256 + (q * 4 + rr) * 16 + r] = acc[rr];
    __syncthreads();
    const int base = blockIdx.x * 512;   // 32 tokens * 16
    Bu[base + tid]       = red[tid]       + red[256 + tid];
    Bu[base + 256 + tid] = red[512 + tid] + red[768 + tid];
}

// ---------------------------------------------------------------------------
// kA: per chunk — M_t via register Chebyshev eval, e_c via wave-0 replay,
// P_c = F(sum/32)^32 (5 LDS squarings).
// ---------------------------------------------------------------------------
__global__ __launch_bounds__(256) void kA_chunk(
    const float* __restrict__ Gt, const float* __restrict__ delta,
    const float* __restrict__ Bu,
    float* __restrict__ P, float* __restrict__ e)
{
    __shared__ float dl[LCH];
    __shared__ float sd[1];
    __shared__ float Bus[LCH * NST];
    __shared__ float Mlds[LCH * 256];
    __shared__ float Ps[16 * 17];
    const int tid = threadIdx.x;
    const size_t g = blockIdx.x;
    if (tid < LCH) dl[tid] = delta[g * LCH + tid];
    for (int idx = tid; idx < LCH * NST; idx += 256)
        Bus[idx] = Bu[g * (size_t)(LCH * NST) + idx];
    float gr[NCHEB];
    {
        const float4* gp = (const float4*)(Gt + (size_t)tid * NCHEB);
#pragma unroll
        for (int qq = 0; qq < NCHEB / 4; ++qq) {
            float4 v = gp[qq];
            gr[qq*4+0] = v.x; gr[qq*4+1] = v.y; gr[qq*4+2] = v.z; gr[qq*4+3] = v.w;
        }
    }
    __syncthreads();
    if (tid == 0) {
        float s = 0.f;
        for (int t = 0; t < LCH; ++t) s += dl[t];
        sd[0] = s;
    }
    for (int t = 0; t < LCH; ++t) {
        const float x = 2.f * dl[t] - 1.f;
        float acc = fmaf(gr[1], x, gr[0]);
        float tm2 = 1.f, tm1 = x;
#pragma unroll
        for (int m = 2; m < NCHEB; ++m) {
            const float tm = fmaf(2.f * x, tm1, -tm2);
            acc = fmaf(gr[m], tm, acc);
            tm2 = tm1; tm1 = tm;
        }
        Mlds[t * 256 + tid] = acc;
    }
    __syncthreads();
    float S;
    {
        const float xp = 2.f * (sd[0] * (1.f / LCH)) - 1.f;
        float acc = fmaf(gr[1], xp, gr[0]);
        float tm2 = 1.f, tm1 = xp;
#pragma unroll
        for (int m = 2; m < NCHEB; ++m) {
            const float tm = fmaf(2.f * xp, tm1, -tm2);
            acc = fmaf(gr[m], tm, acc);
            tm2 = tm1; tm1 = tm;
        }
        S = acc;
    }
    const int i = tid >> 4, j = tid & 15;
#pragma unroll
    for (int r = 0; r < 5; ++r) {
        Ps[i*17 + j] = S;
        __syncthreads();
        float ns = 0.f;
#pragma unroll
        for (int k = 0; k < 16; ++k)
            ns = fmaf(Ps[i*17 + k], Ps[k*17 + j], ns);
        __syncthreads();
        S = ns;
    }
    P[g * 256 + tid] = S;
    if (tid < 16) {
        float h = 0.f;
        for (int t = 0; t < LCH; ++t) {
            float hn = Bus[t * 16 + tid];
#pragma unroll
            for (int i2 = 0; i2 < 16; ++i2)
                hn = fmaf(__shfl(h, i2, 64), Mlds[t * 256 + i2 * 16 + tid], hn);
            h = hn;
        }
        e[g * NST + tid] = h;
    }
}

// ---------------------------------------------------------------------------
// k4: serial scan over the 64 chunk summaries of each batch.
// ---------------------------------------------------------------------------
__global__ __launch_bounds__(256) void k4_scan(
    const float* __restrict__ P, const float* __restrict__ e,
    float* __restrict__ hin)
{
    __shared__ float Pl[32 * 272];
    __shared__ float el[32 * NST];
    const int tid = threadIdx.x;
    const int b = blockIdx.x;
    float h = 0.f;
    for (int half = 0; half < 2; ++half) {
        const int c0 = half * 32;
        for (int idx = tid; idx < 32*256; idx += 256) {
            const int c = idx >> 8, ij = idx & 255, i = ij >> 4, jj = ij & 15;
            Pl[c*272 + i*17 + jj] = P[((size_t)(b*CPB + c0 + c)) * 256 + ij];
        }
        for (int idx = tid; idx < 32*NST; idx += 256)
            el[idx] = e[((size_t)(b*CPB + c0)) * NST + idx];
        __syncthreads();
        if (tid < 64) {
            const int j = tid & 15;
            for (int c = 0; c < 32; ++c) {
                if (tid < 16) hin[((size_t)(b*CPB + c0 + c)) * NST + j] = h;
                float hn = el[c*16 + j];
#pragma unroll
                for (int i2 = 0; i2 < 16; ++i2)
                    hn = fmaf(__shfl(h, i2, 64), Pl[c*272 + i2*17 + j], hn);
                h = hn;
            }
        }
        __syncthreads();
    }
}

// ---------------------------------------------------------------------------
// k5: recompute M from delta (register Chebyshev), replay from hin, fused
// projection y = h C^T + D*u.
// ---------------------------------------------------------------------------
__global__ __launch_bounds__(256) void k5_out(
    const float* __restrict__ Gt, const float* __restrict__ delta,
    const float* __restrict__ Bu, const float* __restrict__ hin,
    const float* __restrict__ u, const float* __restrict__ C_mat,
    const float* __restrict__ D, float* __restrict__ y)
{
    __shared__ float dl[LCH];
    __shared__ float Bus[LCH * NST];
    __shared__ float Mlds[LCH * 256];
    __shared__ __align__(16) float Hs[LCH * NST];
    const int tid = threadIdx.x;
    const size_t g = blockIdx.x;
    if (tid < LCH) dl[tid] = delta[g * LCH + tid];
    for (int idx = tid; idx < LCH * NST; idx += 256)
        Bus[idx] = Bu[g * (size_t)(LCH * NST) + idx];
    float gr[NCHEB];
    {
        const float4* gp = (const float4*)(Gt + (size_t)tid * NCHEB);
#pragma unroll
        for (int qq = 0; qq < NCHEB / 4; ++qq) {
            float4 v = gp[qq];
            gr[qq*4+0] = v.x; gr[qq*4+1] = v.y; gr[qq*4+2] = v.z; gr[qq*4+3] = v.w;
        }
    }
    __syncthreads();
    for (int t = 0; t < LCH; ++t) {
        const float x = 2.f * dl[t] - 1.f;
        float acc = fmaf(gr[1], x, gr[0]);
        float tm2 = 1.f, tm1 = x;
#pragma unroll
        for (int m = 2; m < NCHEB; ++m) {
            const float tm = fmaf(2.f * x, tm1, -tm2);
            acc = fmaf(gr[m], tm, acc);
            tm2 = tm1; tm1 = tm;
        }
        Mlds[t * 256 + tid] = acc;
    }
    __syncthreads();
    if (tid < 16) {
        float h = hin[g * NST + tid];
        for (int t = 0; t < LCH; ++t) {
            float hn = Bus[t * 16 + tid];
#pragma unroll
            for (int i2 = 0; i2 < 16; ++i2)
                hn = fmaf(__shfl(h, i2, 64), Mlds[t * 256 + i2 * 16 + tid], hn);
            h = hn;
            Hs[t * 16 + tid] = h;
        }
    }
    __syncthreads();
    const int d0 = tid * 4;
    float4 cr[4][4];
#pragma unroll
    for (int r = 0; r < 4; ++r)
#pragma unroll
        for (int qq = 0; qq < 4; ++qq)
            cr[r][qq] = ((const float4*)C_mat)[(d0 + r) * 4 + qq];
    const float4 dv = ((const float4*)D)[tid];
    for (int t = 0; t < LCH; ++t) {
        const size_t row = (g * LCH + t) * DIMSZ;
        const float4 uv = ((const float4*)(u + row))[tid];
        float y0 = dv.x * uv.x, y1 = dv.y * uv.y, y2 = dv.z * uv.z, y3 = dv.w * uv.w;
#pragma unroll
        for (int qq = 0; qq < 4; ++qq) {
            const float4 hq = *((const float4*)&Hs[t*16 + qq*4]);
            y0 = fmaf(hq.x, cr[0][qq].x, y0); y0 = fmaf(hq.y, cr[0][qq].y, y0);
            y0 = fmaf(hq.z, cr[0][qq].z, y0); y0 = fmaf(hq.w, cr[0][qq].w, y0);
            y1 = fmaf(hq.x, cr[1][qq].x, y1); y1 = fmaf(hq.y, cr[1][qq].y, y1);
            y1 = fmaf(hq.z, cr[1][qq].z, y1); y1 = fmaf(hq.w, cr[1][qq].w, y1);
            y2 = fmaf(hq.x, cr[2][qq].x, y2); y2 = fmaf(hq.y, cr[2][qq].y, y2);
            y2 = fmaf(hq.z, cr[2][qq].z, y2); y2 = fmaf(hq.w, cr[2][qq].w, y2);
            y3 = fmaf(hq.x, cr[3][qq].x, y3); y3 = fmaf(hq.y, cr[3][qq].y, y3);
            y3 = fmaf(hq.z, cr[3][qq].z, y3); y3 = fmaf(hq.w, cr[3][qq].w, y3);
        }
        float4 ov; ov.x = y0; ov.y = y1; ov.z = y2; ov.w = y3;
        ((float4*)(y + row))[tid] = ov;
    }
}

// ---------------------------------------------------------------------------
extern "C" void kernel_launch(void* const* d_in, const int* in_sizes, int n_in,
                              void* d_out, int out_size, void* d_ws, size_t ws_size,
                              hipStream_t stream)
{
    const float* u     = (const float*)d_in[0];
    const float* gate  = (const float*)d_in[1];
    const float* A_log = (const float*)d_in[2];
    const float* B_mat = (const float*)d_in[3];
    const float* C_mat = (const float*)d_in[4];
    const float* D     = (const float*)d_in[5];
    const float* dt_w  = (const float*)d_in[6];
    const float* dt_b  = (const float*)d_in[7];
    float* y = (float*)d_out;

    float* ws = (float*)d_ws;
    size_t o = 0;
    float* Fn    = ws + o; o += 32 * 256;
    float* Gt    = ws + o; o += 256 * NCHEB;
    float* delta = ws + o; o += (size_t)BATCH * SEQ;
    float* Bu    = ws + o; o += (size_t)BATCH * SEQ * NST;
    float* P     = ws + o; o += (size_t)NCHUNK * 256;
    float* e     = ws + o; o += (size_t)NCHUNK * NST;
    float* hin   = ws + o; o += (size_t)NCHUNK * NST;
    unsigned short* Bfh = (unsigned short*)(ws + o); o += 8192;
    unsigned short* Bfl = (unsigned short*)(ws + o); o += 8192;
    unsigned short* Wfh = (unsigned short*)(ws + o); o += 8192;
    unsigned short* Wfl = (unsigned short*)(ws + o); o += 8192;

    sA_nodes<<<NCHEB, 256, 0, stream>>>(A_log, Fn);
    sB_setup<<<NCHEB + 8, 256, 0, stream>>>(Fn, B_mat, dt_w, Gt, Bfh, Bfl, Wfh, Wfl);
    k1a_delta<<<BATCH * SEQ / 4, 256, 0, stream>>>(gate, dt_w, dt_b, delta);
    k1b_bu  <<<BATCH * SEQ / 32, 256, 0, stream>>>(u, Bfh, Bfl, Bu);
    kA_chunk<<<NCHUNK, 256, 0, stream>>>(Gt, delta, Bu, P, e);
    k4_scan <<<BATCH,  256, 0, stream>>>(P, e, hin);
    k5_out  <<<NCHUNK, 256, 0, stream>>>(Gt, delta, Bu, hin, u, C_mat, D, y);
}